// Round 1
// baseline (735.974 us; speedup 1.0000x reference)
//
#include <hip/hip_runtime.h>
#include <hip/hip_bf16.h>

#define B_ 32
#define P_ 512
#define Q_ 64
#define E_ 300
#define KP 320          // E padded to multiple of 32 for MFMA K-steps
#define H_ 256
#define HH_ 128
#define NEG (-1e7f)
#define BP (B_*P_)
#define BQ (B_*Q_)

typedef __attribute__((ext_vector_type(8))) short bf16x8;
typedef __attribute__((ext_vector_type(4))) float f32x4;

// ---- static device workspace (fully rewritten every call) ----
__device__ __hip_bfloat16 g_ep[BP][KP];      // gathered passage embeddings (bf16)
__device__ __hip_bfloat16 g_eq[BQ][KP];      // gathered question embeddings
__device__ __hip_bfloat16 g_wp[768][KP];     // combined passage wih (f dir rows 0..383, b dir 384..767)
__device__ __hip_bfloat16 g_wq[768][KP];     // combined question wih
__device__ float g_biasp[768];               // bih (+ bhh for r,z gates)
__device__ float g_biasq[768];
__device__ float g_xp[BP*768];               // passage input projections
__device__ float g_xq[BQ*768];               // question input projections
__device__ float g_penc[BP*H_];              // BiGRU passage encodings (f32)
__device__ float g_qenc[BQ*H_];              // BiGRU question encodings

struct PrepArgs { const float* wih[4]; const float* bih[4]; const float* bhh[4]; };
struct GruArgs  { const float* whh[4]; const float* bhh[4]; const int* ptok; const int* qtok; };

// ---------------- weight repack + bias fold ----------------
__global__ __launch_bounds__(64) void k_prepw(PrepArgs pa) {
    int r = blockIdx.x;                 // 0..1535
    int pq = r / 768, col = r % 768;
    int dir = col / 384, within = col % 384, gate = within / 128;
    int idx = pq * 2 + dir;             // {p_f,p_b,q_f,q_b}
    const float* wsrc = pa.wih[idx] + within * E_;
    __hip_bfloat16* dst = pq ? g_wq[col] : g_wp[col];
    for (int c = threadIdx.x; c < KP; c += 64)
        dst[c] = __float2bfloat16(c < E_ ? wsrc[c] : 0.f);
    if (threadIdx.x == 0) {
        float bsum = pa.bih[idx][within] + (gate < 2 ? pa.bhh[idx][within] : 0.f);
        (pq ? g_biasq : g_biasp)[col] = bsum;
    }
}

// ---------------- embedding gather (f32 -> bf16, K padded) ----------------
__global__ __launch_bounds__(256) void k_gather(const int* pass, const int* ques, const float* emb) {
    int row = blockIdx.x * 4 + (threadIdx.x >> 6);
    int lane = threadIdx.x & 63;
    const int* tsrc; __hip_bfloat16* dst; int r;
    if (row < BP) { r = row; tsrc = pass; dst = &g_ep[r][0]; }
    else          { r = row - BP; tsrc = ques; dst = &g_eq[r][0]; }
    int tk = tsrc[r];
    const float* src = emb + (long)tk * E_;
    #pragma unroll
    for (int i = 0; i < 5; i++) {
        int c = i * 64 + lane;
        float v = (c < E_) ? src[c] : 0.f;
        dst[c] = __float2bfloat16(v);
    }
}

// ---------------- input-projection GEMM: xp = ep @ wih^T + bias ----------------
// A: [M][KP] bf16, B: [768][KP] bf16 (B^T form), C: [M][768] f32
__global__ __launch_bounds__(256) void k_gemm(int isQ) {
    const __hip_bfloat16* A  = isQ ? &g_eq[0][0] : &g_ep[0][0];
    const __hip_bfloat16* Bw = isQ ? &g_wq[0][0] : &g_wp[0][0];
    const float* bias = isQ ? g_biasq : g_biasp;
    float* C = isQ ? g_xq : g_xp;
    __shared__ __hip_bfloat16 As[128][40];   // pad 32->40 to break bank stride
    __shared__ __hip_bfloat16 Bs[128][40];
    int m0 = blockIdx.x * 128, n0 = blockIdx.y * 128;
    int tid = threadIdx.x, lane = tid & 63, w = tid >> 6;
    int wm = (w & 1) * 64, wn = (w >> 1) * 64;
    f32x4 acc[4][4] = {};
    int lr = tid >> 1, lc = (tid & 1) * 16;
    for (int kt = 0; kt < KP; kt += 32) {
        *(bf16x8*)&As[lr][lc]   = *(const bf16x8*)&A [(m0 + lr) * KP + kt + lc];
        *(bf16x8*)&As[lr][lc+8] = *(const bf16x8*)&A [(m0 + lr) * KP + kt + lc + 8];
        *(bf16x8*)&Bs[lr][lc]   = *(const bf16x8*)&Bw[(n0 + lr) * KP + kt + lc];
        *(bf16x8*)&Bs[lr][lc+8] = *(const bf16x8*)&Bw[(n0 + lr) * KP + kt + lc + 8];
        __syncthreads();
        int kb = (lane >> 4) * 8, l15 = lane & 15;
        bf16x8 af[4], bfr[4];
        #pragma unroll
        for (int i = 0; i < 4; i++) af[i]  = *(bf16x8*)&As[wm + i*16 + l15][kb];
        #pragma unroll
        for (int j = 0; j < 4; j++) bfr[j] = *(bf16x8*)&Bs[wn + j*16 + l15][kb];
        #pragma unroll
        for (int i = 0; i < 4; i++)
            #pragma unroll
            for (int j = 0; j < 4; j++)
                acc[i][j] = __builtin_amdgcn_mfma_f32_16x16x32_bf16(af[i], bfr[j], acc[i][j], 0, 0, 0);
        __syncthreads();
    }
    int l15 = lane & 15, lr4 = (lane >> 4) * 4;
    #pragma unroll
    for (int j = 0; j < 4; j++) {
        int n = n0 + wn + j * 16 + l15;
        float bn = bias[n];
        #pragma unroll
        for (int i = 0; i < 4; i++) {
            int mb = m0 + wm + i * 16 + lr4;
            #pragma unroll
            for (int q = 0; q < 4; q++)
                C[(long)(mb + q) * 768 + n] = acc[i][j][q] + bn;
        }
    }
}

// ---------------- GRU recurrence: 1 block per (which,batch,dir) chain ----------------
// 384 threads: thread j owns whh row j in VGPRs; h broadcast via LDS.
__global__ __launch_bounds__(384, 2) void k_gru(GruArgs ga) {
    int cid = blockIdx.x;
    int isQ = cid >> 6, loc = cid & 63, b = loc >> 1, dir = loc & 1;
    int T = isQ ? Q_ : P_;
    const int* tok = isQ ? ga.qtok : ga.ptok;
    const float* xp = isQ ? g_xq : g_xp;
    float* outp = isQ ? g_qenc : g_penc;
    const float* whh = ga.whh[isQ * 2 + dir];
    const float* bhh = ga.bhh[isQ * 2 + dir];
    int j = threadIdx.x;
    float wv[128];
    {
        const float4* wr = (const float4*)(whh + j * HH_);
        #pragma unroll
        for (int i = 0; i < 32; i++) {
            float4 v = wr[i];
            wv[4*i] = v.x; wv[4*i+1] = v.y; wv[4*i+2] = v.z; wv[4*i+3] = v.w;
        }
    }
    float bn = (j >= 256) ? bhh[j] : 0.f;   // bhh_n kept out of the GEMM bias fold
    __shared__ float sh[2][HH_];
    __shared__ float shp[384];
    if (j < HH_) sh[0][j] = 0.f;
    __syncthreads();
    int cur = 0;
    const int dcol = dir * 384;
    int t0 = dir ? T - 1 : 0;
    float xv   = xp[(long)(b * T + t0) * 768 + dcol + j];
    float xn_v = (j < HH_) ? xp[(long)(b * T + t0) * 768 + dcol + 256 + j] : 0.f;
    int tk = tok[b * T + t0];
    for (int st = 0; st < T; st++) {
        int t = dir ? (T - 1 - st) : st;
        int sn = (st + 1 < T) ? st + 1 : st;
        int t2 = dir ? (T - 1 - sn) : sn;
        float acc = 0.f;
        const float4* h4p = (const float4*)sh[cur];
        #pragma unroll
        for (int i = 0; i < 32; i++) {
            float4 h4 = h4p[i];             // uniform address -> LDS broadcast
            acc = fmaf(wv[4*i],   h4.x, acc);
            acc = fmaf(wv[4*i+1], h4.y, acc);
            acc = fmaf(wv[4*i+2], h4.z, acc);
            acc = fmaf(wv[4*i+3], h4.w, acc);
        }
        shp[j] = (j < 256) ? (acc + xv) : (acc + bn);
        // prefetch next step (hides HBM/L2 latency under gate phase + next dot)
        float xv_n = xp[(long)(b * T + t2) * 768 + dcol + j];
        float xn_n = (j < HH_) ? xp[(long)(b * T + t2) * 768 + dcol + 256 + j] : 0.f;
        int tk_n = tok[b * T + t2];
        __syncthreads();
        if (j < HH_) {
            float r = 1.f / (1.f + __expf(-shp[j]));
            float z = 1.f / (1.f + __expf(-shp[HH_ + j]));
            float ta = xn_v + r * shp[256 + j];
            ta = fminf(fmaxf(ta, -15.f), 15.f);
            float e2 = __expf(2.f * ta);
            float n = (e2 - 1.f) / (e2 + 1.f);
            float hold = sh[cur][j];
            float hnew = tk ? ((1.f - z) * n + z * hold) : hold;
            sh[cur ^ 1][j] = hnew;
            outp[(long)(b * T + t) * H_ + dir * HH_ + j] = tk ? hnew : 0.f;
        }
        __syncthreads();
        cur ^= 1; xv = xv_n; xn_v = xn_n; tk = tk_n;
    }
}

// ---------------- fused attention + output heads ----------------
#define QPAD 260
__global__ __launch_bounds__(256) void k_attn(const int* pass, const int* ques,
        const float* attn_w, const float* attn_b, const float* start_w,
        const float* start_b, const float* end_w, const float* end_b, float* out) {
    __shared__ float qs[Q_][QPAD];
    __shared__ float pw3[H_];
    __shared__ float lrow[Q_];
    __shared__ float probs[Q_];
    __shared__ float s2v[Q_];
    __shared__ int   qmS[Q_];
    __shared__ float red[4], redA[4], redB[4];
    __shared__ float awpart[4][QPAD];
    int b = blockIdx.x >> 6, pch = blockIdx.x & 63;
    int tid = threadIdx.x, lane = tid & 63, wid = tid >> 6;
    for (int i = tid; i < Q_ * H_; i += 256) {
        int q = i >> 8, h = i & 255;
        qs[q][h] = g_qenc[(long)(b * Q_ + q) * H_ + h];
    }
    if (tid < Q_) qmS[tid] = (ques[b * Q_ + tid] != 0);
    __syncthreads();
    int q4 = tid >> 2, part = tid & 3;
    {   // s2[q] = dot(qenc[q], w2)
        float p2 = 0.f;
        #pragma unroll 8
        for (int i = 0; i < 64; i++)
            p2 += qs[q4][part * 64 + i] * attn_w[256 + part * 64 + i];
        p2 += __shfl_xor(p2, 1);
        p2 += __shfl_xor(p2, 2);
        if (part == 0) s2v[q4] = p2;
    }
    __syncthreads();
    float ab = attn_b[0], sb = start_b[0], ebv = end_b[0];
    for (int pi = 0; pi < 8; pi++) {
        int p = pch * 8 + pi;
        float pv = g_penc[(long)(b * P_ + p) * H_ + tid];
        pw3[tid] = pv * attn_w[512 + tid];
        float r1 = pv * attn_w[tid];
        #pragma unroll
        for (int s = 1; s < 64; s <<= 1) r1 += __shfl_xor(r1, s);
        if (lane == 0) red[wid] = r1;
        __syncthreads();                                  // (A) pw3 + red
        float s1 = red[0] + red[1] + red[2] + red[3];
        float acc = 0.f;
        #pragma unroll
        for (int i = 0; i < 16; i++) {
            float4 qv = *(const float4*)&qs[q4][part * 64 + i * 4];
            float4 wv = *(const float4*)&pw3[part * 64 + i * 4];
            acc += qv.x * wv.x + qv.y * wv.y + qv.z * wv.z + qv.w * wv.w;
        }
        acc += __shfl_xor(acc, 1);
        acc += __shfl_xor(acc, 2);
        if (part == 0) lrow[q4] = qmS[q4] ? (s1 + s2v[q4] + acc + ab) : NEG;
        __syncthreads();                                  // (B) lrow
        if (tid < 64) {
            float v = lrow[tid];
            float m = v;
            #pragma unroll
            for (int s = 1; s < 64; s <<= 1) m = fmaxf(m, __shfl_xor(m, s));
            float e = __expf(v - m);
            float ss = e;
            #pragma unroll
            for (int s = 1; s < 64; s <<= 1) ss += __shfl_xor(ss, s);
            probs[tid] = e / ss;
        }
        __syncthreads();                                  // (C) probs
        // attw: wave w sums q in [16w,16w+16), lane = h/4 (conflict-free float4)
        float4 aw4 = {0.f, 0.f, 0.f, 0.f};
        #pragma unroll
        for (int qq = 0; qq < 16; qq++) {
            int q = wid * 16 + qq;
            float pq = probs[q];
            float4 qv = *(const float4*)&qs[q][lane * 4];
            aw4.x = fmaf(pq, qv.x, aw4.x);
            aw4.y = fmaf(pq, qv.y, aw4.y);
            aw4.z = fmaf(pq, qv.z, aw4.z);
            aw4.w = fmaf(pq, qv.w, aw4.w);
        }
        *(float4*)&awpart[wid][lane * 4] = aw4;
        __syncthreads();                                  // (D0) awpart
        float aw = awpart[0][tid] + awpart[1][tid] + awpart[2][tid] + awpart[3][tid];
        float spv = pv * start_w[tid] + aw * start_w[256 + tid] + pv * aw * start_w[512 + tid];
        float epv = pv * end_w[tid]   + aw * end_w[256 + tid]   + pv * aw * end_w[512 + tid];
        #pragma unroll
        for (int s = 1; s < 64; s <<= 1) {
            spv += __shfl_xor(spv, s);
            epv += __shfl_xor(epv, s);
        }
        if (lane == 0) { redA[wid] = spv; redB[wid] = epv; }
        __syncthreads();                                  // (D) redA/B
        if (tid == 0) {
            int pm = (pass[b * P_ + p] != 0);
            float sv = redA[0] + redA[1] + redA[2] + redA[3] + sb;
            float ev = redB[0] + redB[1] + redB[2] + redB[3] + ebv;
            out[b * P_ + p]       = pm ? sv : NEG;
            out[BP + b * P_ + p]  = pm ? ev : NEG;
        }
        __syncthreads();                                  // (E) end of row
    }
}

// ---------------- log_softmax over P per (batch, start/end) ----------------
__global__ __launch_bounds__(256) void k_lsm(float* out) {
    int b = blockIdx.x >> 1, which = blockIdx.x & 1;
    const float* src = out + which * BP + b * P_;
    int tid = threadIdx.x;
    float v0 = src[tid], v1 = src[tid + 256];
    __shared__ float red[4];
    float m = fmaxf(v0, v1);
    #pragma unroll
    for (int s = 1; s < 64; s <<= 1) m = fmaxf(m, __shfl_xor(m, s));
    if ((tid & 63) == 0) red[tid >> 6] = m;
    __syncthreads();
    m = fmaxf(fmaxf(red[0], red[1]), fmaxf(red[2], red[3]));
    __syncthreads();
    float ss = __expf(v0 - m) + __expf(v1 - m);
    #pragma unroll
    for (int s = 1; s < 64; s <<= 1) ss += __shfl_xor(ss, s);
    if ((tid & 63) == 0) red[tid >> 6] = ss;
    __syncthreads();
    float lse = m + logf(red[0] + red[1] + red[2] + red[3]);
    float* dst = out + (2 + which) * BP + b * P_;
    dst[tid] = v0 - lse;
    dst[tid + 256] = v1 - lse;
}

extern "C" void kernel_launch(void* const* d_in, const int* in_sizes, int n_in,
                              void* d_out, int out_size, void* d_ws, size_t ws_size,
                              hipStream_t stream) {
    const int* pass = (const int*)d_in[0];
    const int* ques = (const int*)d_in[1];
    const float* emb = (const float*)d_in[2];
    PrepArgs pa; GruArgs ga;
    const int base[4] = {3, 7, 11, 15};   // p_f, p_b, q_f, q_b blocks of 4 inputs
    for (int i = 0; i < 4; i++) {
        pa.wih[i] = (const float*)d_in[base[i] + 0];
        ga.whh[i] = (const float*)d_in[base[i] + 1];
        pa.bih[i] = (const float*)d_in[base[i] + 2];
        pa.bhh[i] = (const float*)d_in[base[i] + 3];
        ga.bhh[i] = pa.bhh[i];
    }
    ga.ptok = pass; ga.qtok = ques;
    const float* attn_w  = (const float*)d_in[19];
    const float* attn_b  = (const float*)d_in[20];
    const float* start_w = (const float*)d_in[21];
    const float* start_b = (const float*)d_in[22];
    const float* end_w   = (const float*)d_in[23];
    const float* end_b   = (const float*)d_in[24];
    float* out = (float*)d_out;

    k_prepw <<<dim3(1536), dim3(64), 0, stream>>>(pa);
    k_gather<<<dim3((BP + BQ) / 4), dim3(256), 0, stream>>>(pass, ques, emb);
    k_gemm  <<<dim3(BP / 128, 6), dim3(256), 0, stream>>>(0);
    k_gemm  <<<dim3(BQ / 128, 6), dim3(256), 0, stream>>>(1);
    k_gru   <<<dim3(128), dim3(384), 0, stream>>>(ga);
    k_attn  <<<dim3(B_ * 64), dim3(256), 0, stream>>>(pass, ques, attn_w, attn_b,
                                                      start_w, start_b, end_w, end_b, out);
    k_lsm   <<<dim3(64), dim3(256), 0, stream>>>(out);
}

// Round 2
// 603.402 us; speedup vs baseline: 1.2197x; 1.2197x over previous
//
#include <hip/hip_runtime.h>
#include <hip/hip_bf16.h>

#define B_ 32
#define P_ 512
#define Q_ 64
#define E_ 300
#define KP 320          // E padded to multiple of 32 for MFMA K-steps
#define H_ 256
#define HH_ 128
#define NEG (-1e7f)
#define BP (B_*P_)
#define BQ (B_*Q_)

typedef __attribute__((ext_vector_type(8))) short bf16x8;
typedef __attribute__((ext_vector_type(4))) float f32x4;

// ---- static device workspace (fully rewritten every call) ----
__device__ __hip_bfloat16 g_ep[BP][KP];      // gathered passage embeddings (bf16)
__device__ __hip_bfloat16 g_eq[BQ][KP];      // gathered question embeddings
__device__ __hip_bfloat16 g_wp[768][KP];     // combined passage wih (f dir rows 0..383, b dir 384..767)
__device__ __hip_bfloat16 g_wq[768][KP];     // combined question wih
__device__ float g_biasp[768];               // bih (+ bhh for r,z gates)
__device__ float g_biasq[768];
__device__ float g_xp[BP*768];               // passage input projections
__device__ float g_xq[BQ*768];               // question input projections
__device__ float g_penc[BP*H_];              // BiGRU passage encodings (f32)
__device__ float g_qenc[BQ*H_];              // BiGRU question encodings

struct PrepArgs { const float* wih[4]; const float* bih[4]; const float* bhh[4]; };
struct GruArgs  { const float* whh[4]; const float* bhh[4]; const int* ptok; const int* qtok; };

// ---------------- weight repack + bias fold ----------------
__global__ __launch_bounds__(64) void k_prepw(PrepArgs pa) {
    int r = blockIdx.x;                 // 0..1535
    int pq = r / 768, col = r % 768;
    int dir = col / 384, within = col % 384, gate = within / 128;
    int idx = pq * 2 + dir;             // {p_f,p_b,q_f,q_b}
    const float* wsrc = pa.wih[idx] + within * E_;
    __hip_bfloat16* dst = pq ? g_wq[col] : g_wp[col];
    for (int c = threadIdx.x; c < KP; c += 64)
        dst[c] = __float2bfloat16(c < E_ ? wsrc[c] : 0.f);
    if (threadIdx.x == 0) {
        float bsum = pa.bih[idx][within] + (gate < 2 ? pa.bhh[idx][within] : 0.f);
        (pq ? g_biasq : g_biasp)[col] = bsum;
    }
}

// ---------------- embedding gather (f32 -> bf16, K padded) ----------------
__global__ __launch_bounds__(256) void k_gather(const int* pass, const int* ques, const float* emb) {
    int row = blockIdx.x * 4 + (threadIdx.x >> 6);
    int lane = threadIdx.x & 63;
    const int* tsrc; __hip_bfloat16* dst; int r;
    if (row < BP) { r = row; tsrc = pass; dst = &g_ep[r][0]; }
    else          { r = row - BP; tsrc = ques; dst = &g_eq[r][0]; }
    int tk = tsrc[r];
    const float* src = emb + (long)tk * E_;
    #pragma unroll
    for (int i = 0; i < 5; i++) {
        int c = i * 64 + lane;
        float v = (c < E_) ? src[c] : 0.f;
        dst[c] = __float2bfloat16(v);
    }
}

// ---------------- input-projection GEMM: xp = ep @ wih^T + bias ----------------
// A: [M][KP] bf16, B: [768][KP] bf16 (B^T form), C: [M][768] f32
__global__ __launch_bounds__(256) void k_gemm(int isQ) {
    const __hip_bfloat16* A  = isQ ? &g_eq[0][0] : &g_ep[0][0];
    const __hip_bfloat16* Bw = isQ ? &g_wq[0][0] : &g_wp[0][0];
    const float* bias = isQ ? g_biasq : g_biasp;
    float* C = isQ ? g_xq : g_xp;
    __shared__ __hip_bfloat16 As[128][40];   // pad 32->40 to break bank stride
    __shared__ __hip_bfloat16 Bs[128][40];
    int m0 = blockIdx.x * 128, n0 = blockIdx.y * 128;
    int tid = threadIdx.x, lane = tid & 63, w = tid >> 6;
    int wm = (w & 1) * 64, wn = (w >> 1) * 64;
    f32x4 acc[4][4] = {};
    int lr = tid >> 1, lc = (tid & 1) * 16;
    for (int kt = 0; kt < KP; kt += 32) {
        *(bf16x8*)&As[lr][lc]   = *(const bf16x8*)&A [(m0 + lr) * KP + kt + lc];
        *(bf16x8*)&As[lr][lc+8] = *(const bf16x8*)&A [(m0 + lr) * KP + kt + lc + 8];
        *(bf16x8*)&Bs[lr][lc]   = *(const bf16x8*)&Bw[(n0 + lr) * KP + kt + lc];
        *(bf16x8*)&Bs[lr][lc+8] = *(const bf16x8*)&Bw[(n0 + lr) * KP + kt + lc + 8];
        __syncthreads();
        int kb = (lane >> 4) * 8, l15 = lane & 15;
        bf16x8 af[4], bfr[4];
        #pragma unroll
        for (int i = 0; i < 4; i++) af[i]  = *(bf16x8*)&As[wm + i*16 + l15][kb];
        #pragma unroll
        for (int j = 0; j < 4; j++) bfr[j] = *(bf16x8*)&Bs[wn + j*16 + l15][kb];
        #pragma unroll
        for (int i = 0; i < 4; i++)
            #pragma unroll
            for (int j = 0; j < 4; j++)
                acc[i][j] = __builtin_amdgcn_mfma_f32_16x16x32_bf16(af[i], bfr[j], acc[i][j], 0, 0, 0);
        __syncthreads();
    }
    int l15 = lane & 15, lr4 = (lane >> 4) * 4;
    #pragma unroll
    for (int j = 0; j < 4; j++) {
        int n = n0 + wn + j * 16 + l15;
        float bn = bias[n];
        #pragma unroll
        for (int i = 0; i < 4; i++) {
            int mb = m0 + wm + i * 16 + lr4;
            #pragma unroll
            for (int q = 0; q < 4; q++)
                C[(long)(mb + q) * 768 + n] = acc[i][j][q] + bn;
        }
    }
}

// ---------------- GRU recurrence: 1 block per (which,batch,dir) chain ----------------
// 768 threads, 2-way K-split: thread j owns half of whh row (j%384) in 16 float4
// VGPRs. h broadcast via wave-uniform ds_read_b128 (khalf is wave-uniform: 384=6 waves).
__global__ __launch_bounds__(768, 1) void k_gru(GruArgs ga) {
    int cid = blockIdx.x;               // 0..127
    int isQ = cid >> 6, loc = cid & 63, b = loc >> 1, dir = loc & 1;
    int T = isQ ? Q_ : P_;
    const int* tok = isQ ? ga.qtok : ga.ptok;
    const float* xp = isQ ? g_xq : g_xp;
    float* outp = isQ ? g_qenc : g_penc;
    const float* whh = ga.whh[isQ * 2 + dir];
    const float* bhh = ga.bhh[isQ * 2 + dir];
    int j = threadIdx.x;                // 0..767
    int khalf = (j >= 384);
    int r = j - khalf * 384;            // weight row 0..383
    float4 wv[16];
    {
        const float4* wr = (const float4*)(whh + r * HH_ + khalf * 64);
        #pragma unroll
        for (int i = 0; i < 16; i++) wv[i] = wr[i];
    }
    float bn = (khalf == 1 && r >= 256) ? bhh[r] : 0.f;  // bhh_n (inside r-multiply)
    __shared__ float sh[2][HH_];        // double-buffered h
    __shared__ float shp[2][384];       // K-split partial pre-activations
    __shared__ float xnv[HH_];          // x contribution of n-gate
    if (j < HH_) sh[0][j] = 0.f;
    __syncthreads();
    int cur = 0;
    const int dcol = dir * 384;
    long xbase = (long)b * T;
    int t0 = dir ? T - 1 : 0;
    float xv = (khalf == 0) ? xp[(xbase + t0) * 768 + dcol + r] : 0.f;
    int tk = tok[xbase + t0];
    for (int st = 0; st < T; st++) {
        int t = dir ? (T - 1 - st) : st;
        int sn = (st + 1 < T) ? st + 1 : st;
        int t2 = dir ? (T - 1 - sn) : sn;
        float a0 = 0.f, a1 = 0.f, a2 = 0.f, a3 = 0.f;
        const float4* h4 = (const float4*)(&sh[cur][0] + khalf * 64);
        #pragma unroll
        for (int i = 0; i < 4; i++) {
            float4 w0 = wv[4*i], w1 = wv[4*i+1], w2 = wv[4*i+2], w3 = wv[4*i+3];
            float4 h0 = h4[4*i], h1 = h4[4*i+1], h2 = h4[4*i+2], h3 = h4[4*i+3];
            a0 = fmaf(w0.x, h0.x, a0); a0 = fmaf(w0.y, h0.y, a0);
            a0 = fmaf(w0.z, h0.z, a0); a0 = fmaf(w0.w, h0.w, a0);
            a1 = fmaf(w1.x, h1.x, a1); a1 = fmaf(w1.y, h1.y, a1);
            a1 = fmaf(w1.z, h1.z, a1); a1 = fmaf(w1.w, h1.w, a1);
            a2 = fmaf(w2.x, h2.x, a2); a2 = fmaf(w2.y, h2.y, a2);
            a2 = fmaf(w2.z, h2.z, a2); a2 = fmaf(w2.w, h2.w, a2);
            a3 = fmaf(w3.x, h3.x, a3); a3 = fmaf(w3.y, h3.y, a3);
            a3 = fmaf(w3.z, h3.z, a3); a3 = fmaf(w3.w, h3.w, a3);
        }
        float part = (a0 + a1) + (a2 + a3);
        if (khalf == 0) {
            if (r < 256) part += xv;    // bih(+bhh r,z) already folded via GEMM bias
            else xnv[r - 256] = xv;     // n-gate x part applied after r-multiply
        } else {
            part += bn;
        }
        shp[khalf][r] = part;
        // prefetch next step's x and token (hidden under gate phase + next dot)
        float xv_n = (khalf == 0) ? xp[(xbase + t2) * 768 + dcol + r] : 0.f;
        int tk_n = tok[xbase + t2];     // uniform -> scalar load
        __syncthreads();
        if (j < HH_) {
            float pr = shp[0][j]       + shp[1][j];
            float pz = shp[0][128 + j] + shp[1][128 + j];
            float hn = shp[0][256 + j] + shp[1][256 + j];
            float rg = 1.f / (1.f + __expf(-pr));
            float zg = 1.f / (1.f + __expf(-pz));
            float ta = xnv[j] + rg * hn;
            ta = fminf(fmaxf(ta, -15.f), 15.f);
            float e2 = __expf(2.f * ta);
            float n = (e2 - 1.f) / (e2 + 1.f);
            float hold = sh[cur][j];
            float hnew = tk ? ((1.f - zg) * n + zg * hold) : hold;
            sh[cur ^ 1][j] = hnew;
            outp[(xbase + t) * H_ + dir * HH_ + j] = tk ? hnew : 0.f;
        }
        __syncthreads();
        cur ^= 1; xv = xv_n; tk = tk_n;
    }
}

// ---------------- fused attention + output heads ----------------
#define QPAD 260
__global__ __launch_bounds__(256) void k_attn(const int* pass, const int* ques,
        const float* attn_w, const float* attn_b, const float* start_w,
        const float* start_b, const float* end_w, const float* end_b, float* out) {
    __shared__ float qs[Q_][QPAD];
    __shared__ float pw3[H_];
    __shared__ float lrow[Q_];
    __shared__ float probs[Q_];
    __shared__ float s2v[Q_];
    __shared__ int   qmS[Q_];
    __shared__ float red[4], redA[4], redB[4];
    __shared__ float awpart[4][QPAD];
    int b = blockIdx.x >> 6, pch = blockIdx.x & 63;
    int tid = threadIdx.x, lane = tid & 63, wid = tid >> 6;
    for (int i = tid; i < Q_ * H_; i += 256) {
        int q = i >> 8, h = i & 255;
        qs[q][h] = g_qenc[(long)(b * Q_ + q) * H_ + h];
    }
    if (tid < Q_) qmS[tid] = (ques[b * Q_ + tid] != 0);
    __syncthreads();
    int q4 = tid >> 2, part = tid & 3;
    {   // s2[q] = dot(qenc[q], w2)
        float p2 = 0.f;
        #pragma unroll 8
        for (int i = 0; i < 64; i++)
            p2 += qs[q4][part * 64 + i] * attn_w[256 + part * 64 + i];
        p2 += __shfl_xor(p2, 1);
        p2 += __shfl_xor(p2, 2);
        if (part == 0) s2v[q4] = p2;
    }
    __syncthreads();
    float ab = attn_b[0], sb = start_b[0], ebv = end_b[0];
    for (int pi = 0; pi < 8; pi++) {
        int p = pch * 8 + pi;
        float pv = g_penc[(long)(b * P_ + p) * H_ + tid];
        pw3[tid] = pv * attn_w[512 + tid];
        float r1 = pv * attn_w[tid];
        #pragma unroll
        for (int s = 1; s < 64; s <<= 1) r1 += __shfl_xor(r1, s);
        if (lane == 0) red[wid] = r1;
        __syncthreads();                                  // (A) pw3 + red
        float s1 = red[0] + red[1] + red[2] + red[3];
        float acc = 0.f;
        #pragma unroll
        for (int i = 0; i < 16; i++) {
            float4 qv = *(const float4*)&qs[q4][part * 64 + i * 4];
            float4 wv = *(const float4*)&pw3[part * 64 + i * 4];
            acc += qv.x * wv.x + qv.y * wv.y + qv.z * wv.z + qv.w * wv.w;
        }
        acc += __shfl_xor(acc, 1);
        acc += __shfl_xor(acc, 2);
        if (part == 0) lrow[q4] = qmS[q4] ? (s1 + s2v[q4] + acc + ab) : NEG;
        __syncthreads();                                  // (B) lrow
        if (tid < 64) {
            float v = lrow[tid];
            float m = v;
            #pragma unroll
            for (int s = 1; s < 64; s <<= 1) m = fmaxf(m, __shfl_xor(m, s));
            float e = __expf(v - m);
            float ss = e;
            #pragma unroll
            for (int s = 1; s < 64; s <<= 1) ss += __shfl_xor(ss, s);
            probs[tid] = e / ss;
        }
        __syncthreads();                                  // (C) probs
        // attw: wave w sums q in [16w,16w+16), lane = h/4 (conflict-free float4)
        float4 aw4 = {0.f, 0.f, 0.f, 0.f};
        #pragma unroll
        for (int qq = 0; qq < 16; qq++) {
            int q = wid * 16 + qq;
            float pq = probs[q];
            float4 qv = *(const float4*)&qs[q][lane * 4];
            aw4.x = fmaf(pq, qv.x, aw4.x);
            aw4.y = fmaf(pq, qv.y, aw4.y);
            aw4.z = fmaf(pq, qv.z, aw4.z);
            aw4.w = fmaf(pq, qv.w, aw4.w);
        }
        *(float4*)&awpart[wid][lane * 4] = aw4;
        __syncthreads();                                  // (D0) awpart
        float aw = awpart[0][tid] + awpart[1][tid] + awpart[2][tid] + awpart[3][tid];
        float spv = pv * start_w[tid] + aw * start_w[256 + tid] + pv * aw * start_w[512 + tid];
        float epv = pv * end_w[tid]   + aw * end_w[256 + tid]   + pv * aw * end_w[512 + tid];
        #pragma unroll
        for (int s = 1; s < 64; s <<= 1) {
            spv += __shfl_xor(spv, s);
            epv += __shfl_xor(epv, s);
        }
        if (lane == 0) { redA[wid] = spv; redB[wid] = epv; }
        __syncthreads();                                  // (D) redA/B
        if (tid == 0) {
            int pm = (pass[b * P_ + p] != 0);
            float sv = redA[0] + redA[1] + redA[2] + redA[3] + sb;
            float ev = redB[0] + redB[1] + redB[2] + redB[3] + ebv;
            out[b * P_ + p]       = pm ? sv : NEG;
            out[BP + b * P_ + p]  = pm ? ev : NEG;
        }
        __syncthreads();                                  // (E) end of row
    }
}

// ---------------- log_softmax over P per (batch, start/end) ----------------
__global__ __launch_bounds__(256) void k_lsm(float* out) {
    int b = blockIdx.x >> 1, which = blockIdx.x & 1;
    const float* src = out + which * BP + b * P_;
    int tid = threadIdx.x;
    float v0 = src[tid], v1 = src[tid + 256];
    __shared__ float red[4];
    float m = fmaxf(v0, v1);
    #pragma unroll
    for (int s = 1; s < 64; s <<= 1) m = fmaxf(m, __shfl_xor(m, s));
    if ((tid & 63) == 0) red[tid >> 6] = m;
    __syncthreads();
    m = fmaxf(fmaxf(red[0], red[1]), fmaxf(red[2], red[3]));
    __syncthreads();
    float ss = __expf(v0 - m) + __expf(v1 - m);
    #pragma unroll
    for (int s = 1; s < 64; s <<= 1) ss += __shfl_xor(ss, s);
    if ((tid & 63) == 0) red[tid >> 6] = ss;
    __syncthreads();
    float lse = m + logf(red[0] + red[1] + red[2] + red[3]);
    float* dst = out + (2 + which) * BP + b * P_;
    dst[tid] = v0 - lse;
    dst[tid + 256] = v1 - lse;
}

extern "C" void kernel_launch(void* const* d_in, const int* in_sizes, int n_in,
                              void* d_out, int out_size, void* d_ws, size_t ws_size,
                              hipStream_t stream) {
    const int* pass = (const int*)d_in[0];
    const int* ques = (const int*)d_in[1];
    const float* emb = (const float*)d_in[2];
    PrepArgs pa; GruArgs ga;
    const int base[4] = {3, 7, 11, 15};   // p_f, p_b, q_f, q_b blocks of 4 inputs
    for (int i = 0; i < 4; i++) {
        pa.wih[i] = (const float*)d_in[base[i] + 0];
        ga.whh[i] = (const float*)d_in[base[i] + 1];
        pa.bih[i] = (const float*)d_in[base[i] + 2];
        pa.bhh[i] = (const float*)d_in[base[i] + 3];
        ga.bhh[i] = pa.bhh[i];
    }
    ga.ptok = pass; ga.qtok = ques;
    const float* attn_w  = (const float*)d_in[19];
    const float* attn_b  = (const float*)d_in[20];
    const float* start_w = (const float*)d_in[21];
    const float* start_b = (const float*)d_in[22];
    const float* end_w   = (const float*)d_in[23];
    const float* end_b   = (const float*)d_in[24];
    float* out = (float*)d_out;

    k_prepw <<<dim3(1536), dim3(64), 0, stream>>>(pa);
    k_gather<<<dim3((BP + BQ) / 4), dim3(256), 0, stream>>>(pass, ques, emb);
    k_gemm  <<<dim3(BP / 128, 6), dim3(256), 0, stream>>>(0);
    k_gemm  <<<dim3(BQ / 128, 6), dim3(256), 0, stream>>>(1);
    k_gru   <<<dim3(128), dim3(768), 0, stream>>>(ga);
    k_attn  <<<dim3(B_ * 64), dim3(256), 0, stream>>>(pass, ques, attn_w, attn_b,
                                                      start_w, start_b, end_w, end_b, out);
    k_lsm   <<<dim3(64), dim3(256), 0, stream>>>(out);
}